// Round 18
// baseline (225.503 us; speedup 1.0000x reference)
//
#include <hip/hip_runtime.h>
#include <hip/hip_cooperative_groups.h>
#include <math.h>

namespace cg = cooperative_groups;

#define HIDDEN 64
#define SEQ 128
#define BATCH 64
#define NPTS (BATCH * SEQ)   // 8192
#define NBLK 192             // 64 LSTM + 128 EE, cooperative co-resident
#define TMAXV 20.0f
#define L2E 1.4426950408889634f
#define LN2 0.6931471805599453f

typedef float v2f __attribute__((ext_vector_type(2)));

__device__ __forceinline__ float fexp2(float x) { return __builtin_amdgcn_exp2f(x); }
__device__ __forceinline__ float flog2(float x) { return __builtin_amdgcn_logf(x); }
__device__ __forceinline__ float frcp(float x)  { return __builtin_amdgcn_rcpf(x); }
__device__ __forceinline__ float fsigmoid(float x) { return frcp(1.0f + fexp2(-x * L2E)); }
__device__ __forceinline__ float ftanh(float x)    { return 1.0f - 2.0f * frcp(1.0f + fexp2(2.0f * x * L2E)); }

// Raw barrier: orders LDS only (lgkmcnt), does NOT drain vmcnt.
__device__ __forceinline__ void barrier_lds_only() {
    asm volatile("s_waitcnt lgkmcnt(0)" ::: "memory");
    __builtin_amdgcn_s_barrier();
}

// ---- DPP helpers (VALU pipe, no LDS) ----
template <int CTRL>
__device__ __forceinline__ float dpp_mov(float x) {
    int r = __builtin_amdgcn_update_dpp(0, __float_as_int(x), CTRL, 0xf, 0xf, false);
    return __int_as_float(r);
}
__device__ __forceinline__ float wave_sum_dpp(float x) {
    x += dpp_mov<0x111>(x);   // row_shr:1
    x += dpp_mov<0x112>(x);   // row_shr:2
    x += dpp_mov<0x114>(x);   // row_shr:4
    x += dpp_mov<0x118>(x);   // row_shr:8  -> lane 16r+15 = row sum
    x += dpp_mov<0x142>(x);   // row_bcast:15
    x += dpp_mov<0x143>(x);   // row_bcast:31 -> lane 63 = total
    return __int_as_float(__builtin_amdgcn_readlane(__float_as_int(x), 63));
}

__device__ __forceinline__ float wave_sum_shfl(float v) {
    v += __shfl_xor(v, 1);  v += __shfl_xor(v, 2);  v += __shfl_xor(v, 4);
    v += __shfl_xor(v, 8);  v += __shfl_xor(v, 16); v += __shfl_xor(v, 32);
    return v;
}

// ONE cooperative kernel replacing {memset, gen_and_ee, ll_le}:
//   total-gen has been a constant ~88.5us across r0-r17 while ll_le+memset is
//   ~10us of real work -> the bulk is 3-node launch/graph overhead + gaps.
// Phase 1 (pre-sync):  blocks 0-63 = r16 LSTM (byte-identical, 66us floor);
//                      blocks 64-191 = EE, per-wave partials DEFERRED in regs;
//                      block 0 thread 0 zeroes out (all atomics are post-sync).
// grid.sync()          (device-scope fence: tl and out=0 visible to all)
// Phase 2 (post-sync): EE waves flush partials (same per-wave atomicAdd set as
//                      before); 512 ll_le tiles grid-strided over 192 blocks,
//                      tile math and per-tile sum structure bit-identical.
__global__ __launch_bounds__(256) void fused(
    const float* __restrict__ upool,   // [B,S]
    const float* __restrict__ texp,    // [B,S]
    const float* __restrict__ Wih,     // [256]
    const float* __restrict__ Whh,     // [256,64]
    const float* __restrict__ bih,     // [256]
    const float* __restrict__ bhh,     // [256]
    const float* __restrict__ Vw,      // [64]
    const float* __restrict__ Vb,      // [1]
    float* __restrict__ tl,            // [NPTS] workspace
    float* __restrict__ out)           // [1] loss accumulator
{
    // [0,4096)      phase1 EE: qbuf float2[2048] / phase2: qbuf4 float4[512]
    // [4096,4160)   hx_s[64]
    // [4160,4288)   lu_s[128]
    // [4288,4292)   red[4] (phase 2)
    __shared__ __align__(16) float smem[4292];

    const int bid = blockIdx.x;
    const int tid = threadIdx.x;

    float ee_partial = 0.0f;           // deferred EE wave sum (flushed post-sync)

    if (bid == 0 && tid == 0) out[0] = 0.0f;   // replaces hipMemsetAsync

    if (bid < BATCH) {
        // ---------------- r16 LSTM rollout (byte-identical) ----------------
        const int l   = tid & 63;            // lane
        const int wv  = tid >> 6;            // wave 0..3
        const int u   = (wv << 4) + (l >> 2);// hidden unit 0..63
        const int g   = l & 3;               // gate 0=i 1=f 2=g 3=o
        const int row = (g << 6) + u;        // gate row 0..255

        float* hx_s = smem + 4096;
        float* lu_s = smem + 4160;

        v2f w2[32];
        const float4* wrow = (const float4*)(Whh + row * 64);
        #pragma unroll
        for (int k = 0; k < 16; ++k) {
            float4 v = wrow[k];
            w2[2 * k]     = (v2f){v.x, v.y};
            w2[2 * k + 1] = (v2f){v.z, v.w};
        }
        const float bias = bih[row] + bhh[row];
        const float wih  = Wih[row];
        const float vw   = Vw[l];
        const float vb   = Vb[0];

        if (tid < SEQ) lu_s[tid] = -flog2(upool[bid * SEQ + tid]) * LN2;
        if (tid < 64) hx_s[tid] = 0.0f;
        float cx = 0.0f;
        barrier_lds_only();

        float sg0 = (vb > 0.0f) ? (vb + 1.0f) : fexp2(vb * L2E);
        float cum = lu_s[0] * frcp(sg0);
        float keep = (tid == 0) ? cum : 0.0f;

        #pragma unroll 1
        for (int s = 0; s < SEQ - 1; ++s) {
            if (s > 0) {
                float tot = wave_sum_dpp(hx_s[l] * vw);
                float xx  = tot + vb;
                float sg  = (xx > 0.0f) ? (xx + 1.0f) : fexp2(xx * L2E);
                cum += lu_s[s] * frcp(sg);
                keep = (tid == s) ? cum : keep;
            }

            const float4* h4 = (const float4*)hx_s;
            v2f a0 = {0.f, 0.f}, a1 = {0.f, 0.f}, a2 = {0.f, 0.f}, a3 = {0.f, 0.f};
            #pragma unroll
            for (int k = 0; k < 16; k += 2) {
                float4 va = h4[k];
                float4 vbq = h4[k + 1];
                a0 = a0 + w2[2 * k]     * (v2f){va.x, va.y};
                a1 = a1 + w2[2 * k + 1] * (v2f){va.z, va.w};
                a2 = a2 + w2[2 * k + 2] * (v2f){vbq.x, vbq.y};
                a3 = a3 + w2[2 * k + 3] * (v2f){vbq.z, vbq.w};
            }
            v2f aa = (a0 + a1) + (a2 + a3);
            float gin = (aa.x + aa.y) + bias + cum * wih;
            float sig = fsigmoid(gin);
            float tnh = ftanh(gin);
            float a = (g == 2) ? tnh : sig;

            float ig = dpp_mov<0x00>(a);
            float fg = dpp_mov<0x55>(a);
            float gg = dpp_mov<0xAA>(a);
            float og = dpp_mov<0xFF>(a);

            cx = fg * cx + ig * gg;
            float hx = og * ftanh(cx);
            if (g == 0) hx_s[u] = hx;
            barrier_lds_only();
        }
        {
            float tot = wave_sum_dpp(hx_s[l] * vw);
            float xx  = tot + vb;
            float sg  = (xx > 0.0f) ? (xx + 1.0f) : fexp2(xx * L2E);
            cum += lu_s[SEQ - 1] * frcp(sg);
            keep = (tid == SEQ - 1) ? cum : keep;
        }
        if (tid < SEQ) tl[bid * SEQ + tid] = keep;
    } else {
        // ------------- EE term (r16-identical math, deferred add) -------------
        const int eb = bid - BATCH;      // 0..127
        const int pc = eb & 31;          // p-chunk (256 points)
        const int qs = eb >> 5;          // q-split (2048 points)

        float2* qbuf = (float2*)smem;    // [2048]

        const int p = pc * 256 + tid;
        const float tp = texp[p];
        const float mp = (tp < TMAXV && tp > 0.0f) ? 1.0f : 0.0f;

        const int q0 = qs * 2048;
        for (int i = tid; i < 2048; i += 256) {
            float tq = texp[q0 + i];
            float mq = (tq < TMAXV && tq > 0.0f) ? 1.0f : 0.0f;
            qbuf[i] = make_float2(tq, mq);
        }
        __syncthreads();

        float acc = 0.0f;
        #pragma unroll 4
        for (int i = 0; i < 2048; ++i) {
            float2 qq = qbuf[i];
            float d = tp - qq.x;
            acc = fmaf(qq.y, fexp2(d * d * (-L2E)), acc);
        }
        acc *= mp;
        ee_partial = wave_sum_shfl(acc);   // flushed after grid sync
    }

    cg::this_grid().sync();   // tl + out=0 visible device-wide

    // EE flush: same per-wave atomicAdd contribution set as the 3-kernel version
    if (bid >= BATCH && (tid & 63) == 0) atomicAdd(out, ee_partial);

    // ---------------- ll_le: 512 tiles grid-strided over 192 blocks ----------
    {
        float4* qbuf4 = (float4*)smem;   // [512]
        float*  red   = smem + 4288;     // [4]

        for (int t = bid; t < 512; t += NBLK) {
            const int pc = t & 31;       // p-chunk (256 points)
            const int qs = t >> 5;       // q-split (512 points)

            __syncthreads();             // previous tile fully read

            const int p = pc * 256 + tid;
            const float tlp = tl[p];
            const float mlp = (tlp < TMAXV && tlp > 0.0f) ? 1.0f : 0.0f;

            const int q0 = qs * 512;
            for (int i = tid; i < 512; i += 256) {
                float tq = tl[q0 + i];
                float mq = (tq < TMAXV && tq > 0.0f) ? 1.0f : 0.0f;
                float te = texp[q0 + i];
                float me = (te < TMAXV && te > 0.0f) ? 1.0f : 0.0f;
                qbuf4[i] = make_float4(tq, mq, te, me);
            }
            __syncthreads();

            float val = 0.0f;
            if (__ballot(mlp != 0.0f) != 0ULL) {
                float a_ll = 0.0f, a_le = 0.0f;
                #pragma unroll 4
                for (int i = 0; i < 512; ++i) {
                    float4 q = qbuf4[i];
                    float d1 = tlp - q.x;
                    a_ll = fmaf(q.y, fexp2(d1 * d1 * (-L2E)), a_ll);
                    float d2 = tlp - q.z;
                    a_le = fmaf(q.w, fexp2(d2 * d2 * (-L2E)), a_le);
                }
                val = mlp * (a_ll - 2.0f * a_le);
            }

            val = wave_sum_shfl(val);
            if ((tid & 63) == 0) red[tid >> 6] = val;
            __syncthreads();
            if (tid == 0) atomicAdd(out, red[0] + red[1] + red[2] + red[3]);
        }
    }
}

extern "C" void kernel_launch(void* const* d_in, const int* in_sizes, int n_in,
                              void* d_out, int out_size, void* d_ws, size_t ws_size,
                              hipStream_t stream) {
    const float* upool = (const float*)d_in[0];
    const float* texp  = (const float*)d_in[1];
    const float* Wih   = (const float*)d_in[2];
    const float* Whh   = (const float*)d_in[3];
    const float* bih   = (const float*)d_in[4];
    const float* bhh   = (const float*)d_in[5];
    const float* Vw    = (const float*)d_in[6];
    const float* Vb    = (const float*)d_in[7];
    float* out = (float*)d_out;
    float* tl  = (float*)d_ws;   // 8192 floats = 32 KB

    void* args[] = {(void*)&upool, (void*)&texp, (void*)&Wih, (void*)&Whh,
                    (void*)&bih, (void*)&bhh, (void*)&Vw, (void*)&Vb,
                    (void*)&tl, (void*)&out};
    hipLaunchCooperativeKernel((void*)fused, dim3(NBLK), dim3(256), args, 0, stream);
}

// Round 19
// 156.048 us; speedup vs baseline: 1.4451x; 1.4451x over previous
//
#include <hip/hip_runtime.h>
#include <math.h>

#define HIDDEN 64
#define SEQ 128
#define BATCH 64
#define NPTS (BATCH * SEQ)   // 8192
#define TMAXV 20.0f
#define L2E 1.4426950408889634f
#define LN2 0.6931471805599453f

typedef float v2f __attribute__((ext_vector_type(2)));

__device__ __forceinline__ float fexp2(float x) { return __builtin_amdgcn_exp2f(x); }
__device__ __forceinline__ float flog2(float x) { return __builtin_amdgcn_logf(x); }
__device__ __forceinline__ float frcp(float x)  { return __builtin_amdgcn_rcpf(x); }
__device__ __forceinline__ float fsigmoid(float x) { return frcp(1.0f + fexp2(-x * L2E)); }
__device__ __forceinline__ float ftanh(float x)    { return 1.0f - 2.0f * frcp(1.0f + fexp2(2.0f * x * L2E)); }

// Raw barrier: orders LDS only (lgkmcnt), does NOT drain vmcnt.
__device__ __forceinline__ void barrier_lds_only() {
    asm volatile("s_waitcnt lgkmcnt(0)" ::: "memory");
    __builtin_amdgcn_s_barrier();
}

// ---- DPP helpers (VALU pipe, no LDS) ----
template <int CTRL>
__device__ __forceinline__ float dpp_mov(float x) {
    int r = __builtin_amdgcn_update_dpp(0, __float_as_int(x), CTRL, 0xf, 0xf, false);
    return __int_as_float(r);
}
__device__ __forceinline__ float wave_sum_dpp(float x) {
    x += dpp_mov<0x111>(x);   // row_shr:1
    x += dpp_mov<0x112>(x);   // row_shr:2
    x += dpp_mov<0x114>(x);   // row_shr:4
    x += dpp_mov<0x118>(x);   // row_shr:8  -> lane 16r+15 = row sum
    x += dpp_mov<0x142>(x);   // row_bcast:15
    x += dpp_mov<0x143>(x);   // row_bcast:31 -> lane 63 = total
    return __int_as_float(__builtin_amdgcn_readlane(__float_as_int(x), 63));
}

__device__ __forceinline__ float wave_sum_shfl(float v) {
    v += __shfl_xor(v, 1);  v += __shfl_xor(v, 2);  v += __shfl_xor(v, 4);
    v += __shfl_xor(v, 8);  v += __shfl_xor(v, 16); v += __shfl_xor(v, 32);
    return v;
}

// Blocks [0,64): LSTM rollout, one batch per block, 256 threads.
// QUAD-GATE MAPPING (r16, best measured: 154.6us total / 66us gen): thread
// (wave w, lane l) owns gate row (l&3)*64 + 16w + (l>>2); lanes 4j..4j+3 hold
// gates i,f,g,o of unit u=16w+j. Gate exchange = 4 quad_perm DPP movs; one
// lgkm-only barrier/step; sigma at loop top (r3's exact DPP association).
// 18-round verdict: gen is the structural floor of a 127-step data-dependent
// recurrence at 1 wave/SIMD (~1250 cy/step); weight residency, AGPRs, LDS,
// pipe-splitting, 2-batch TLP, and cooperative fusion all measured >= this.
// The remaining ~86us of total is harness-fixed (r18: single-launch fusion
// left the gap unchanged at 85.1us).
// Blocks [64,192): expert-expert MMD term.
__global__ __launch_bounds__(256) void gen_and_ee(
    const float* __restrict__ upool,   // [B,S]
    const float* __restrict__ texp,    // [B,S]
    const float* __restrict__ Wih,     // [256]
    const float* __restrict__ Whh,     // [256,64]
    const float* __restrict__ bih,     // [256]
    const float* __restrict__ bhh,     // [256]
    const float* __restrict__ Vw,      // [64]
    const float* __restrict__ Vb,      // [1]
    float* __restrict__ tl,            // [NPTS] workspace
    float* __restrict__ out)           // [1] loss accumulator
{
    // [0,4096)      qbuf float2[2048] (EE branch)
    // [4096,4160)   hx_s[64]  (shared state, published once per step)
    // [4160,4288)   lu_s[128]
    __shared__ __align__(16) float smem[4288];

    const int bid = blockIdx.x;
    const int tid = threadIdx.x;

    if (bid < BATCH) {
        const int l   = tid & 63;            // lane
        const int wv  = tid >> 6;            // wave 0..3
        const int u   = (wv << 4) + (l >> 2);// hidden unit 0..63
        const int g   = l & 3;               // gate 0=i 1=f 2=g 3=o
        const int row = (g << 6) + u;        // gate row 0..255

        float* hx_s = smem + 4096;
        float* lu_s = smem + 4160;

        // W_hh row (r3-style preload; compiler may sink -- proven fine)
        v2f w2[32];
        const float4* wrow = (const float4*)(Whh + row * 64);
        #pragma unroll
        for (int k = 0; k < 16; ++k) {
            float4 v = wrow[k];
            w2[2 * k]     = (v2f){v.x, v.y};
            w2[2 * k + 1] = (v2f){v.z, v.w};
        }
        const float bias = bih[row] + bhh[row];
        const float wih  = Wih[row];
        const float vw   = Vw[l];            // sigma: lane l multiplies hx_s[l]
        const float vb   = Vb[0];

        if (tid < SEQ) lu_s[tid] = -flog2(upool[bid * SEQ + tid]) * LN2;
        if (tid < 64) hx_s[tid] = 0.0f;
        float cx = 0.0f;
        barrier_lds_only();

        // step 0: hx = 0 -> sigma = elu(Vb)+1 (uniform)
        float sg0 = (vb > 0.0f) ? (vb + 1.0f) : fexp2(vb * L2E);
        float cum = lu_s[0] * frcp(sg0);
        float keep = (tid == 0) ? cum : 0.0f;   // thread t keeps cum of step t

        #pragma unroll 1
        for (int s = 0; s < SEQ - 1; ++s) {
            // sigma/cum update for THIS step (s>0; s=0's cum set pre-loop).
            // Same lane->hx mapping and DPP association as r3 -> bit-exact.
            if (s > 0) {
                float tot = wave_sum_dpp(hx_s[l] * vw);
                float xx  = tot + vb;
                float sg  = (xx > 0.0f) ? (xx + 1.0f) : fexp2(xx * L2E);
                cum += lu_s[s] * frcp(sg);
                keep = (tid == s) ? cum : keep;
            }

            // gate-row dot hx (broadcast b128 reads; r3-identical pairing)
            const float4* h4 = (const float4*)hx_s;
            v2f a0 = {0.f, 0.f}, a1 = {0.f, 0.f}, a2 = {0.f, 0.f}, a3 = {0.f, 0.f};
            #pragma unroll
            for (int k = 0; k < 16; k += 2) {
                float4 va = h4[k];
                float4 vbq = h4[k + 1];
                a0 = a0 + w2[2 * k]     * (v2f){va.x, va.y};
                a1 = a1 + w2[2 * k + 1] * (v2f){va.z, va.w};
                a2 = a2 + w2[2 * k + 2] * (v2f){vbq.x, vbq.y};
                a3 = a3 + w2[2 * k + 3] * (v2f){vbq.z, vbq.w};
            }
            v2f aa = (a0 + a1) + (a2 + a3);
            float gin = (aa.x + aa.y) + bias + cum * wih;
            // compute both, select (no divergence); selected value bit-exact
            float sig = fsigmoid(gin);
            float tnh = ftanh(gin);
            float a = (g == 2) ? tnh : sig;

            // quad exchange: all 4 gates of unit u into every lane of the quad
            float ig = dpp_mov<0x00>(a);   // quad_perm(0,0,0,0)
            float fg = dpp_mov<0x55>(a);   // quad_perm(1,1,1,1)
            float gg = dpp_mov<0xAA>(a);   // quad_perm(2,2,2,2)
            float og = dpp_mov<0xFF>(a);   // quad_perm(3,3,3,3)

            // cell update, redundant across the quad (bit-identical)
            cx = fg * cx + ig * gg;
            float hx = og * ftanh(cx);
            if (g == 0) hx_s[u] = hx;      // 16 consecutive floats/wave: no conflict
            barrier_lds_only();            // the ONLY barrier per step
        }
        // final sigma/cum for step SEQ-1
        {
            float tot = wave_sum_dpp(hx_s[l] * vw);
            float xx  = tot + vb;
            float sg  = (xx > 0.0f) ? (xx + 1.0f) : fexp2(xx * L2E);
            cum += lu_s[SEQ - 1] * frcp(sg);
            keep = (tid == SEQ - 1) ? cum : keep;
        }
        if (tid < SEQ) tl[bid * SEQ + tid] = keep;
    } else {
        // ---------------- expert-expert MMD term ----------------
        const int eb = bid - BATCH;      // 0..127
        const int pc = eb & 31;          // p-chunk (256 points)
        const int qs = eb >> 5;          // q-split (2048 points)

        float2* qbuf = (float2*)smem;    // [2048]

        const int p = pc * 256 + tid;
        const float tp = texp[p];
        const float mp = (tp < TMAXV && tp > 0.0f) ? 1.0f : 0.0f;

        const int q0 = qs * 2048;
        for (int i = tid; i < 2048; i += 256) {
            float tq = texp[q0 + i];
            float mq = (tq < TMAXV && tq > 0.0f) ? 1.0f : 0.0f;
            qbuf[i] = make_float2(tq, mq);
        }
        __syncthreads();

        float acc = 0.0f;
        #pragma unroll 4
        for (int i = 0; i < 2048; ++i) {
            float2 qq = qbuf[i];
            float d = tp - qq.x;
            acc = fmaf(qq.y, fexp2(d * d * (-L2E)), acc);
        }
        acc *= mp;
        acc = wave_sum_shfl(acc);
        if ((tid & 63) == 0) atomicAdd(out, acc);
    }
}

// ll + le terms. Grid (32, 16): 32 p-chunks of 256 x 16 q-splits of 512.
__global__ __launch_bounds__(256) void ll_le(
    const float* __restrict__ texp,
    const float* __restrict__ tl,
    float* __restrict__ out)
{
    __shared__ __align__(16) float4 qbuf[512];
    __shared__ float red[4];

    const int pc = blockIdx.x;
    const int qs = blockIdx.y;
    const int tid = threadIdx.x;

    const int p = pc * 256 + tid;
    const float tlp = tl[p];
    const float mlp = (tlp < TMAXV && tlp > 0.0f) ? 1.0f : 0.0f;

    const int q0 = qs * 512;
    for (int i = tid; i < 512; i += 256) {
        float tq = tl[q0 + i];
        float mq = (tq < TMAXV && tq > 0.0f) ? 1.0f : 0.0f;
        float te = texp[q0 + i];
        float me = (te < TMAXV && te > 0.0f) ? 1.0f : 0.0f;
        qbuf[i] = make_float4(tq, mq, te, me);
    }
    __syncthreads();

    float val = 0.0f;
    // learner times are cumsum of Exp(1) increments: most p-points exceed T_MAX;
    // fully-masked waves skip the whole q-loop (wave-uniform branch).
    if (__ballot(mlp != 0.0f) != 0ULL) {
        float a_ll = 0.0f, a_le = 0.0f;
        #pragma unroll 4
        for (int i = 0; i < 512; ++i) {
            float4 q = qbuf[i];
            float d1 = tlp - q.x;
            a_ll = fmaf(q.y, fexp2(d1 * d1 * (-L2E)), a_ll);
            float d2 = tlp - q.z;
            a_le = fmaf(q.w, fexp2(d2 * d2 * (-L2E)), a_le);
        }
        val = mlp * (a_ll - 2.0f * a_le);
    }

    val = wave_sum_shfl(val);
    if ((tid & 63) == 0) red[tid >> 6] = val;
    __syncthreads();
    if (tid == 0) atomicAdd(out, red[0] + red[1] + red[2] + red[3]);
}

extern "C" void kernel_launch(void* const* d_in, const int* in_sizes, int n_in,
                              void* d_out, int out_size, void* d_ws, size_t ws_size,
                              hipStream_t stream) {
    const float* upool = (const float*)d_in[0];
    const float* texp  = (const float*)d_in[1];
    const float* Wih   = (const float*)d_in[2];
    const float* Whh   = (const float*)d_in[3];
    const float* bih   = (const float*)d_in[4];
    const float* bhh   = (const float*)d_in[5];
    const float* Vw    = (const float*)d_in[6];
    const float* Vb    = (const float*)d_in[7];
    float* out = (float*)d_out;
    float* tl  = (float*)d_ws;   // 8192 floats = 32 KB

    hipMemsetAsync(out, 0, sizeof(float), stream);
    hipLaunchKernelGGL(gen_and_ee, dim3(BATCH + 128), dim3(256), 0, stream,
                       upool, texp, Wih, Whh, bih, bhh, Vw, Vb, tl, out);
    hipLaunchKernelGGL(ll_le, dim3(32, 16), dim3(256), 0, stream, texp, tl, out);
}